// Round 14
// baseline (70.954 us; speedup 1.0000x reference)
//
#include <hip/hip_runtime.h>
#include <hip/hip_bf16.h>
#include <stdint.h>

typedef float  f32x4  __attribute__((ext_vector_type(4)));
typedef float  f32x2  __attribute__((ext_vector_type(2)));
typedef __bf16 bf16x8 __attribute__((ext_vector_type(8)));

#define LROW 40   // (fallback kernel only)

// ---------------- weight prep: f32 -> bf16 [tensor][o][k] ----------------
__global__ __launch_bounds__(256) void wprep_kernel(
    const float* __restrict__ Wq, const float* __restrict__ Wk,
    const float* __restrict__ Wv, __bf16* __restrict__ Wbf)
{
  const int wb = blockIdx.x;           // 0..95
  const int t  = wb >> 5;
  const float* src = (t == 0) ? Wq : (t == 1) ? Wk : Wv;
  const int off = (wb & 31) * 2048 + threadIdx.x * 8;
  f32x4 v0 = *(const f32x4*)(src + off);
  f32x4 v1 = *(const f32x4*)(src + off + 4);
  bf16x8 r;
#pragma unroll
  for (int q = 0; q < 4; ++q) { r[q] = (__bf16)v0[q]; r[q + 4] = (__bf16)v1[q]; }
  *(bf16x8*)(Wbf + t * 65536 + off) = r;
}

// ---------------- fused GEMM: DMA f32 X + in-LDS vectorized transpose -------
// 128(o) x 128(px) tile, BK=32, 8 phases.
// B: DMA raw f32 [32k][128px] (linear dest, per-lane global src does the
//    gather). Per phase, transpose pass: 8x ds_read_b64 (lane = px-pair,
//    8 consecutive k-rows per wave) -> 16 cvt -> 2 vector writes into
//    Bsb[px][36] bf16 (72B rows). Fragment reads then k-contiguous.
// A: DMA bf16 weights, 4-slot XOR swizzle slot^(row&3) (involution).
// Sync: counted vmcnt {8,4,4,4,4,4,0,0}; Bf x3, As x2, Bsb x1 = 73 KB.

#define GLOAD16(GS, LD) \
  __builtin_amdgcn_global_load_lds( \
      (const __attribute__((address_space(1))) uint32_t*)(GS), \
      (__attribute__((address_space(3))) uint32_t*)(LD), 16, 0, 0)

__global__ __launch_bounds__(256) void gemm_fx_kernel(
    const float* __restrict__ blue, const float* __restrict__ white,
    const __bf16* __restrict__ Wbf,
    const float* __restrict__ bq, const float* __restrict__ bk,
    const float* __restrict__ bv,
    __bf16* __restrict__ Qt, __bf16* __restrict__ Kt, __bf16* __restrict__ Vt)
{
  __shared__ __bf16 As[2][128 * 32];   // 8 KB each (DMA dest, linear)
  __shared__ float  Bf[3][32 * 128];   // 16 KB each (DMA dest, linear)
  __shared__ __bf16 Bsb[128 * 36];     // 9 KB transposed bf16, 72B rows

  // XCD-chunked; same-tile panels {K0,V0,K1,V1,Q0,Q1} adjacent (white L2 reuse)
  const int bid = blockIdx.x;                   // 1536 = 8 * 192
  const int lid = (bid & 7) * 192 + (bid >> 3);
  const int nb  = lid / 6;
  const int bt  = lid % 6;
  const int tensor = (bt < 4) ? 1 + (bt & 1) : 0;   // 0:Q 1:K 2:V
  const int ob     = (bt < 4) ? (bt >> 1) : (bt & 1);

  const float*  X    = (tensor == 0) ? blue : white;
  const float*  bias = (tensor == 0) ? bq : (tensor == 1) ? bk : bv;
  __bf16*       Out  = (tensor == 0) ? Qt : (tensor == 1) ? Kt : Vt;
  const __bf16* Wp   = Wbf + tensor * 65536 + ob * 32768;

  const int tid  = threadIdx.x;
  const int lane = tid & 63;
  const int w    = tid >> 6;
  const int wo   = w >> 1;
  const int wn   = w & 1;
  const int lrow = lane & 15;
  const int lks  = lane >> 4;          // k-octet slot 0..3

  const int o0    = ob * 128;
  const int n0    = nb * 128;
  const int batch = n0 >> 12;
  const int p0    = n0 & 4095;
  const int tk0   = p0 >> 4;
  const int trow  = tk0 >> 4;
  const int tcol0 = tk0 & 15;
  const float* Xb = X + (size_t)batch * (256 * 4096);

  // ---- A staging: 2 instrs; idx = w*2+m covers rows idx*16..+15
  const __bf16* gA[2]; int aO[2];
#pragma unroll
  for (int m = 0; m < 2; ++m) {
    const int idx  = w * 2 + m;
    const int row  = idx * 16 + (lane >> 2);
    const int slot = lane & 3;
    const int ps   = slot ^ (row & 3);          // source pre-swizzle (involution)
    gA[m] = Wp + (size_t)row * 256 + ps * 8;    // + kk*32
    aO[m] = idx * 512;                          // bf16 elems (wave-uniform)
  }
  // ---- B staging: 4 instrs; c = m*4+w covers k-rows {2c, 2c+1}
  const float* gB[4]; int bO[4];
#pragma unroll
  for (int m = 0; m < 4; ++m) {
    const int c    = m * 4 + w;
    const int krow = 2 * c + (lane >> 5);
    const int p    = (lane & 31) * 4;           // tile px (4 contiguous)
    const int tl   = p >> 4;
    const int d    = p & 15;                    // d&3 == 0
    const int hw   = (trow * 4 + (d >> 2)) * 64 + (tcol0 + tl) * 4;
    gB[m] = Xb + (size_t)krow * 4096 + hw;      // + kk*32*4096
    bO[m] = c * 256;                            // f32 elems (wave-uniform)
  }

#define STAGE_A(KK, BUF) do {                                  \
    GLOAD16(gA[0] + (KK) * 32, &As[BUF][aO[0]]);               \
    GLOAD16(gA[1] + (KK) * 32, &As[BUF][aO[1]]);               \
  } while (0)

#define STAGE_B(KK, BUF) do {                                  \
    GLOAD16(gB[0] + (size_t)(KK) * 32 * 4096, &Bf[BUF][bO[0]]);\
    GLOAD16(gB[1] + (size_t)(KK) * 32 * 4096, &Bf[BUF][bO[1]]);\
    GLOAD16(gB[2] + (size_t)(KK) * 32 * 4096, &Bf[BUF][bO[2]]);\
    GLOAD16(gB[3] + (size_t)(KK) * 32 * 4096, &Bf[BUF][bO[3]]);\
  } while (0)

  // ---- transpose pass: wave w owns k-rows w*8..w*8+7; lane owns px {2l,2l+1}
#define TRANS(BUF) do {                                                       \
    f32x2 tv[8];                                                              \
    _Pragma("unroll")                                                         \
    for (int r = 0; r < 8; ++r)                                               \
      tv[r] = *(const f32x2*)&Bf[BUF][(w * 8 + r) * 128 + 2 * lane];          \
    bf16x8 e0, e1;                                                            \
    _Pragma("unroll")                                                         \
    for (int r = 0; r < 8; ++r) {                                             \
      e0[r] = (__bf16)tv[r][0]; e1[r] = (__bf16)tv[r][1];                     \
    }                                                                         \
    *(bf16x8*)&Bsb[(2 * lane) * 36 + w * 8]     = e0;                         \
    *(bf16x8*)&Bsb[(2 * lane + 1) * 36 + w * 8] = e1;                         \
  } while (0)

  f32x4 acc[4][4];
#pragma unroll
  for (int i = 0; i < 4; ++i)
#pragma unroll
    for (int j = 0; j < 4; ++j) acc[i][j] = (f32x4)0.0f;

#define COMPUTE(ABUF) do {                                                    \
    bf16x8 af[4], bfr[4];                                                     \
    _Pragma("unroll")                                                         \
    for (int i = 0; i < 4; ++i) {                                             \
      const int row = wo * 64 + i * 16 + lrow;                                \
      af[i] = *(const bf16x8*)&As[ABUF][row * 32 + ((lks ^ (row & 3)) * 8)];  \
    }                                                                         \
    _Pragma("unroll")                                                         \
    for (int j = 0; j < 4; ++j) {                                             \
      const int px = wn * 64 + j * 16 + lrow;                                 \
      bfr[j] = *(const bf16x8*)&Bsb[px * 36 + lks * 8];                       \
    }                                                                         \
    __builtin_amdgcn_s_setprio(1);                                            \
    _Pragma("unroll")                                                         \
    for (int i = 0; i < 4; ++i)                                               \
      _Pragma("unroll")                                                       \
      for (int j = 0; j < 4; ++j)                                             \
        acc[i][j] = __builtin_amdgcn_mfma_f32_16x16x32_bf16(af[i], bfr[j],    \
                                                            acc[i][j], 0,0,0);\
    __builtin_amdgcn_s_setprio(0);                                            \
  } while (0)

  // phase t: bar1(vmcnt) | A(t+1) | TRANS(t) | lgkm+bar2 | COMPUTE(t) | B(t+3)
#define PHASE(T, NW) do {                                                     \
    asm volatile("s_waitcnt vmcnt(" #NW ")" ::: "memory");                    \
    __builtin_amdgcn_sched_barrier(0);                                        \
    __builtin_amdgcn_s_barrier();                                             \
    __builtin_amdgcn_sched_barrier(0);                                        \
    if ((T) + 1 <= 7) STAGE_A((T) + 1, ((T) + 1) & 1);                        \
    TRANS((T) % 3);                                                           \
    asm volatile("s_waitcnt lgkmcnt(0)" ::: "memory");                        \
    __builtin_amdgcn_sched_barrier(0);                                        \
    __builtin_amdgcn_s_barrier();                                             \
    __builtin_amdgcn_sched_barrier(0);                                        \
    COMPUTE((T) & 1);                                                         \
    if ((T) + 3 <= 7) STAGE_B((T) + 3, ((T) + 3) % 3);                        \
  } while (0)

  // prologue: A0, B0, B1, B2 (issue order matters for vmcnt counts)
  STAGE_A(0, 0);
  STAGE_B(0, 0);
  STAGE_B(1, 1);
  STAGE_B(2, 2);

  PHASE(0, 8); PHASE(1, 4); PHASE(2, 4); PHASE(3, 4);
  PHASE(4, 4); PHASE(5, 4); PHASE(6, 0); PHASE(7, 0);
#undef PHASE
#undef COMPUTE
#undef TRANS
#undef STAGE_A
#undef STAGE_B

  // ---- epilogue: bias add, write bf16 layout [b][ti][c][tj][16]
#pragma unroll
  for (int i = 0; i < 4; ++i) {
    const int obase = o0 + wo * 64 + i * 16 + (lane >> 4) * 4;
#pragma unroll
    for (int j = 0; j < 4; ++j) {
      const int n  = n0 + wn * 64 + j * 16 + (lane & 15);
      const int bb = n >> 12;
      const int pp = n & 4095;
      const int tt = pp >> 4;
      const int tii = tt >> 4;
      const int tjj = tt & 15;
      const int dd  = pp & 15;
      const size_t base = ((size_t)(bb * 16 + tii) * 256) * 256 + tjj * 16 + dd;
#pragma unroll
      for (int r = 0; r < 4; ++r) {
        const int o = obase + r;
        const float v = acc[i][j][r] + bias[o];
        Out[base + (size_t)o * 256] = (__bf16)v;
      }
    }
  }
}

// ---------------- fallback: round-2 self-contained projection ----------------
__global__ __launch_bounds__(256) void proj_gemm_kernel(
    const float* __restrict__ blue, const float* __restrict__ white,
    const float* __restrict__ Wq, const float* __restrict__ bq,
    const float* __restrict__ Wk, const float* __restrict__ bk,
    const float* __restrict__ Wv, const float* __restrict__ bv,
    __bf16* __restrict__ Qt, __bf16* __restrict__ Kt, __bf16* __restrict__ Vt)
{
  __shared__ __bf16 As[128 * LROW];
  __shared__ __bf16 Bs[128 * LROW];

  const int bidhw = blockIdx.x;
  const int lid   = (bidhw & 7) * 192 + (bidhw >> 3);
  const int nb    = lid / 6;
  const int bt    = lid % 6;
  const int tensor = (bt < 4) ? 1 + (bt & 1) : 0;
  const int ob     = (bt < 4) ? (bt >> 1) : (bt & 1);

  const float* X    = (tensor == 0) ? blue : white;
  const float* W    = (tensor == 0) ? Wq : (tensor == 1) ? Wk : Wv;
  const float* bias = (tensor == 0) ? bq : (tensor == 1) ? bk : bv;
  __bf16*      Out  = (tensor == 0) ? Qt : (tensor == 1) ? Kt : Vt;

  const int tid  = threadIdx.x;
  const int lane = tid & 63;
  const int wave = tid >> 6;
  const int wo   = wave >> 1;
  const int wn   = wave & 1;

  const int o0 = ob * 128;
  const int n0 = nb * 128;
  const int batch = n0 >> 12;
  const int p0    = n0 & 4095;
  const int tk0   = p0 >> 4;
  const int trow  = tk0 >> 4;
  const int tcol0 = tk0 & 15;
  const float* Xb = X + (size_t)batch * (256 * 4096);

  f32x4 acc[4][4];
#pragma unroll
  for (int i = 0; i < 4; ++i)
#pragma unroll
    for (int j = 0; j < 4; ++j) acc[i][j] = (f32x4)0.0f;

  const int arow  = tid >> 1;
  const int ahalf = tid & 1;
  const int n2   = tid & 63;
  const int ko   = tid >> 6;
  const int nloc = 2 * n2;
  const int tl   = nloc >> 4;
  const int d    = nloc & 15;
  const int hw   = (trow * 4 + (d >> 2)) * 64 + (tcol0 + tl) * 4 + (d & 3);

  const int lrow = lane & 15;
  const int lk   = (lane >> 4) * 8;

  for (int kk = 0; kk < 8; ++kk) {
    const int k0 = kk * 32;
    {
      const float* src = W + (size_t)(o0 + arow) * 256 + k0 + ahalf * 16;
      f32x4 t0 = *(const f32x4*)(src + 0);
      f32x4 t1 = *(const f32x4*)(src + 4);
      f32x4 t2 = *(const f32x4*)(src + 8);
      f32x4 t3 = *(const f32x4*)(src + 12);
      bf16x8 c0, c1;
#pragma unroll
      for (int qq = 0; qq < 4; ++qq) { c0[qq] = (__bf16)t0[qq]; c0[qq + 4] = (__bf16)t1[qq]; }
#pragma unroll
      for (int qq = 0; qq < 4; ++qq) { c1[qq] = (__bf16)t2[qq]; c1[qq + 4] = (__bf16)t3[qq]; }
      __bf16* dst = As + arow * LROW + ahalf * 16;
      *(bf16x8*)(dst + 0) = c0;
      *(bf16x8*)(dst + 8) = c1;
    }
    {
      const float* src = Xb + (size_t)(k0 + ko * 8) * 4096 + hw;
      f32x2 v0 = *(const f32x2*)(src + 0 * 4096);
      f32x2 v1 = *(const f32x2*)(src + 1 * 4096);
      f32x2 v2 = *(const f32x2*)(src + 2 * 4096);
      f32x2 v3 = *(const f32x2*)(src + 3 * 4096);
      f32x2 v4 = *(const f32x2*)(src + 4 * 4096);
      f32x2 v5 = *(const f32x2*)(src + 5 * 4096);
      f32x2 v6 = *(const f32x2*)(src + 6 * 4096);
      f32x2 v7 = *(const f32x2*)(src + 7 * 4096);
      bf16x8 r0, r1;
      r0[0] = (__bf16)v0[0]; r0[1] = (__bf16)v1[0]; r0[2] = (__bf16)v2[0]; r0[3] = (__bf16)v3[0];
      r0[4] = (__bf16)v4[0]; r0[5] = (__bf16)v5[0]; r0[6] = (__bf16)v6[0]; r0[7] = (__bf16)v7[0];
      r1[0] = (__bf16)v0[1]; r1[1] = (__bf16)v1[1]; r1[2] = (__bf16)v2[1]; r1[3] = (__bf16)v3[1];
      r1[4] = (__bf16)v4[1]; r1[5] = (__bf16)v5[1]; r1[6] = (__bf16)v6[1]; r1[7] = (__bf16)v7[1];
      *(bf16x8*)(Bs + (nloc + 0) * LROW + ko * 8) = r0;
      *(bf16x8*)(Bs + (nloc + 1) * LROW + ko * 8) = r1;
    }
    __syncthreads();

    bf16x8 a[4], b[4];
#pragma unroll
    for (int i = 0; i < 4; ++i)
      a[i] = *(const bf16x8*)(As + (wo * 64 + i * 16 + lrow) * LROW + lk);
#pragma unroll
    for (int j = 0; j < 4; ++j)
      b[j] = *(const bf16x8*)(Bs + (wn * 64 + j * 16 + lrow) * LROW + lk);
#pragma unroll
    for (int i = 0; i < 4; ++i)
#pragma unroll
      for (int j = 0; j < 4; ++j)
        acc[i][j] = __builtin_amdgcn_mfma_f32_16x16x32_bf16(a[i], b[j], acc[i][j], 0, 0, 0);
    __syncthreads();
  }

#pragma unroll
  for (int i = 0; i < 4; ++i) {
    const int obase = o0 + wo * 64 + i * 16 + (lane >> 4) * 4;
#pragma unroll
    for (int j = 0; j < 4; ++j) {
      const int n  = n0 + wn * 64 + j * 16 + (lane & 15);
      const int bb = n >> 12;
      const int p  = n & 4095;
      const int tt = p >> 4;
      const int tii = tt >> 4;
      const int tjj = tt & 15;
      const int dd  = p & 15;
      const size_t base = ((size_t)(bb * 16 + tii) * 256) * 256 + tjj * 16 + dd;
#pragma unroll
      for (int r = 0; r < 4; ++r) {
        const int o = obase + r;
        const float v = acc[i][j][r] + bias[o];
        Out[base + (size_t)o * 256] = (__bf16)v;
      }
    }
  }
}

// ---------------- fused neighborhood attention + residual ----------------
__device__ __forceinline__ void unpack8(const uint4 v, float* f) {
  const uint32_t u0 = v.x, u1 = v.y, u2 = v.z, u3 = v.w;
  f[0] = __uint_as_float(u0 << 16); f[1] = __uint_as_float(u0 & 0xffff0000u);
  f[2] = __uint_as_float(u1 << 16); f[3] = __uint_as_float(u1 & 0xffff0000u);
  f[4] = __uint_as_float(u2 << 16); f[5] = __uint_as_float(u2 & 0xffff0000u);
  f[6] = __uint_as_float(u3 << 16); f[7] = __uint_as_float(u3 & 0xffff0000u);
}

__global__ __launch_bounds__(256) void attn_kernel(
    const __bf16* __restrict__ Qt, const __bf16* __restrict__ Kt,
    const __bf16* __restrict__ Vt, const float* __restrict__ blue,
    float* __restrict__ out)
{
  const int j   = blockIdx.x;
  const int bid = (j & 7) * 256 + (j >> 3);
  const int cg  = bid & 15;
  const int ti  = (bid >> 4) & 15;
  const int b   = bid >> 8;

  const int tid = threadIdx.x;
  const int tj  = tid & 15;
  const int cl  = tid >> 4;
  const int c   = cg * 16 + cl;

  float q[16];
  {
    const __bf16* p = Qt + ((((size_t)b * 16 + ti) * 256 + c) * 16 + tj) * 16;
    unpack8(*(const uint4*)p, q);
    unpack8(*(const uint4*)(p + 8), q + 8);
  }

  float s[9];
#pragma unroll
  for (int n = 0; n < 9; ++n) {
    const int yi = ti + n / 3 - 1;
    const int yj = tj + n % 3 - 1;
    float dot = 0.0f;
    if (yi >= 0 && yi < 16 && yj >= 0 && yj < 16) {
      const __bf16* p = Kt + ((((size_t)b * 16 + yi) * 256 + c) * 16 + yj) * 16;
      float kf[16];
      unpack8(*(const uint4*)p, kf);
      unpack8(*(const uint4*)(p + 8), kf + 8);
#pragma unroll
      for (int dd = 0; dd < 16; ++dd) dot = fmaf(q[dd], kf[dd], dot);
    }
    s[n] = dot * 0.25f;
  }

  float m = s[0];
#pragma unroll
  for (int n = 1; n < 9; ++n) m = fmaxf(m, s[n]);
  float w[9], denom = 0.0f;
#pragma unroll
  for (int n = 0; n < 9; ++n) { w[n] = __expf(s[n] - m); denom += w[n]; }
  const float inv = 1.0f / denom;

  float o16[16];
#pragma unroll
  for (int dd = 0; dd < 16; ++dd) o16[dd] = 0.0f;
#pragma unroll
  for (int n = 0; n < 9; ++n) {
    const int yi = ti + n / 3 - 1;
    const int yj = tj + n % 3 - 1;
    if (yi >= 0 && yi < 16 && yj >= 0 && yj < 16) {
      const __bf16* p = Vt + ((((size_t)b * 16 + yi) * 256 + c) * 16 + yj) * 16;
      float vf[16];
      unpack8(*(const uint4*)p, vf);
      unpack8(*(const uint4*)(p + 8), vf + 8);
#pragma unroll
      for (int dd = 0; dd < 16; ++dd) o16[dd] = fmaf(w[n], vf[dd], o16[dd]);
    }
  }

  const size_t pbase = ((size_t)b * 256 + c) * 4096 + (size_t)(ti * 4) * 64 + tj * 4;
#pragma unroll
  for (int r = 0; r < 4; ++r) {
    f32x4 bl = *(const f32x4*)(blue + pbase + r * 64);
    f32x4 ov;
#pragma unroll
    for (int j2 = 0; j2 < 4; ++j2) ov[j2] = bl[j2] + o16[r * 4 + j2] * inv;
    *(f32x4*)(out + pbase + r * 64) = ov;
  }
}

// ---------------- launcher ----------------
extern "C" void kernel_launch(void* const* d_in, const int* in_sizes, int n_in,
                              void* d_out, int out_size, void* d_ws, size_t ws_size,
                              hipStream_t stream) {
  const float* blue  = (const float*)d_in[0];
  const float* white = (const float*)d_in[1];
  const float* Wq = (const float*)d_in[2];
  const float* bq = (const float*)d_in[3];
  const float* Wk = (const float*)d_in[4];
  const float* bk = (const float*)d_in[5];
  const float* Wv = (const float*)d_in[6];
  const float* bv = (const float*)d_in[7];
  float* out = (float*)d_out;

  const size_t tsz = (size_t)8 * 256 * 256 * 16;   // QKV elems per tensor
  __bf16* Qt = (__bf16*)d_ws;
  __bf16* Kt = Qt + tsz;
  __bf16* Vt = Kt + tsz;

  const size_t need = (3 * tsz + 3 * 65536) * sizeof(__bf16);
  if (ws_size >= need) {
    __bf16* Wbf = Vt + tsz;
    wprep_kernel<<<96, 256, 0, stream>>>(Wq, Wk, Wv, Wbf);
    gemm_fx_kernel<<<1536, 256, 0, stream>>>(blue, white, Wbf, bq, bk, bv, Qt, Kt, Vt);
  } else {
    proj_gemm_kernel<<<1536, 256, 0, stream>>>(blue, white, Wq, bq, Wk, bk, Wv, bv, Qt, Kt, Vt);
  }
  attn_kernel<<<2048, 256, 0, stream>>>(Qt, Kt, Vt, blue, out);
}

// Round 15
// 69.718 us; speedup vs baseline: 1.0177x; 1.0177x over previous
//
#include <hip/hip_runtime.h>
#include <hip/hip_bf16.h>
#include <stdint.h>

typedef float  f32x4  __attribute__((ext_vector_type(4)));
typedef float  f32x2  __attribute__((ext_vector_type(2)));
typedef __bf16 bf16x8 __attribute__((ext_vector_type(8)));

#define LROW 40   // (fallback kernel only)

// ---------------- prep: streaming transpose + weight convert ----------------
// blocks 0..255: one (input, b, ti): X f32 [c][hw] -> Xt bf16 [n][c].
// Thread = (channel-octet co, pixel-quad): 8 x f32x4 strided reads
// (128B segments, 1KB/wave-instr) -> 4 x bf16x8 writes (128B segments).
// blocks 256..258: W* f32 -> Wbf bf16 [tensor][o][k] straight copy
__global__ __launch_bounds__(1024) void prep_kernel(
    const float* __restrict__ blue, const float* __restrict__ white,
    const float* __restrict__ Wq, const float* __restrict__ Wk,
    const float* __restrict__ Wv,
    __bf16* __restrict__ Xtb, __bf16* __restrict__ Xtw,
    __bf16* __restrict__ Wbf)
{
  const int bid = blockIdx.x;
  const int tid = threadIdx.x;

  if (bid >= 256) {                       // ---- weights: plain convert
    const int t = bid - 256;
    const float* src = (t == 0) ? Wq : (t == 1) ? Wk : Wv;
    __bf16* dst = Wbf + t * 65536;
#pragma unroll
    for (int it = 0; it < 8; ++it) {
      const int idx = it * 8192 + tid * 8;
      f32x4 v0 = *(const f32x4*)(src + idx);
      f32x4 v1 = *(const f32x4*)(src + idx + 4);
      bf16x8 r;
#pragma unroll
      for (int q = 0; q < 4; ++q) { r[q] = (__bf16)v0[q]; r[q + 4] = (__bf16)v1[q]; }
      *(bf16x8*)(dst + idx) = r;
    }
    return;
  }

  const int srcw = bid >> 7;
  const int rem  = bid & 127;
  const int b    = rem >> 4;
  const int ti   = rem & 15;
  const float* X = srcw ? white : blue;
  __bf16*     Xt = srcw ? Xtw : Xtb;

  const int s  = tid & 7;                 // quad sub-slot
  const int co = (tid >> 3) & 31;         // channel octet
  const int u  = tid >> 8;                // 0..3

  const float* Xb = X + (size_t)b * (256 * 4096);
  __bf16* Xo = Xt + (size_t)b * 4096 * 256;

#pragma unroll
  for (int it = 0; it < 2; ++it) {
    const int qd = it * 32 + u * 8 + s;       // pixel quad 0..63
    const int r  = qd >> 4;                   // hw row within strip
    const int tj = qd & 15;                   // token column
    const int hw = (ti * 4 + r) * 64 + tj * 4;
    const int n0 = ti * 256 + tj * 16 + r * 4;

    f32x4 v[8];
#pragma unroll
    for (int j = 0; j < 8; ++j)
      v[j] = *(const f32x4*)(Xb + (size_t)(co * 8 + j) * 4096 + hw);

#pragma unroll
    for (int i = 0; i < 4; ++i) {
      bf16x8 e;
#pragma unroll
      for (int j = 0; j < 8; ++j) e[j] = (__bf16)v[j][i];
      *(bf16x8*)(Xo + (size_t)(n0 + i) * 256 + co * 8) = e;
    }
  }
}

// ---------------- GEMM: global_load_lds, BK=64, 4 phases ----------------
// 128(o) x 128(px) tile, BK=64, 4 K-steps, double-buffered LDS (64 KB).
// Stage: 8 x GLOAD16/wave (4 A + 4 B), linear LDS dest; source k-chunk
// pre-swizzled slot^=(row&7); ds_read applies the same XOR -> every lane
// gets its canonical chunk (semantics unchanged) and b128 reads are 2-way.
// Counted vmcnt(8) keeps the next stage in flight across barriers.

#define GLOAD16(GS, LD) \
  __builtin_amdgcn_global_load_lds( \
      (const __attribute__((address_space(1))) uint32_t*)(GS), \
      (__attribute__((address_space(3))) uint32_t*)(LD), 16, 0, 0)

__global__ __launch_bounds__(256) void gemm_bk64_kernel(
    const __bf16* __restrict__ Xtb, const __bf16* __restrict__ Xtw,
    const __bf16* __restrict__ Wbf,
    const float* __restrict__ bq, const float* __restrict__ bk,
    const float* __restrict__ bv,
    __bf16* __restrict__ Qt, __bf16* __restrict__ Kt, __bf16* __restrict__ Vt)
{
  __shared__ __bf16 As[2][128 * 64];   // 16 KB each
  __shared__ __bf16 Bs[2][128 * 64];

  // XCD-chunked; same-tile panels {K0,V0,K1,V1,Q0,Q1} adjacent (L2 reuse)
  const int bid = blockIdx.x;                   // 1536 = 8 * 192
  const int lid = (bid & 7) * 192 + (bid >> 3);
  const int nb  = lid / 6;
  const int bt  = lid % 6;
  const int tensor = (bt < 4) ? 1 + (bt & 1) : 0;   // 0:Q 1:K 2:V
  const int ob     = (bt < 4) ? (bt >> 1) : (bt & 1);

  const __bf16* Xt   = (tensor == 0) ? Xtb : Xtw;
  const float*  bias = (tensor == 0) ? bq : (tensor == 1) ? bk : bv;
  __bf16*       Out  = (tensor == 0) ? Qt : (tensor == 1) ? Kt : Vt;
  const __bf16* Wp   = Wbf + tensor * 65536 + ob * 32768;

  const int tid  = threadIdx.x;
  const int lane = tid & 63;
  const int w    = tid >> 6;
  const int wo   = w >> 1;
  const int wn   = w & 1;
  const int lrow = lane & 15;
  const int lks  = lane >> 4;         // k-chunk sub-slot 0..3

  const int o0 = ob * 128;
  const int n0 = nb * 128;

  // ---- staging addressing: instr m covers rows (w*4+m)*8 .. +7, 8 slots
  const __bf16* gAsrc[4];
  const __bf16* gBsrc[4];
  int ldsOff[4];
#pragma unroll
  for (int m = 0; m < 4; ++m) {
    const int i    = w * 4 + m;
    const int row  = i * 8 + (lane >> 3);
    const int slot = lane & 7;
    const int ps   = slot ^ (row & 7);            // source pre-swizzle
    gAsrc[m]  = Wp + (size_t)row * 256 + ps * 8;  // + kk*64
    gBsrc[m]  = Xt + (size_t)(n0 + row) * 256 + ps * 8;
    ldsOff[m] = i * 512;                          // elems (1 KB per instr)
  }

#define STAGE(BUF, KK) do {                                        \
    GLOAD16(gAsrc[0] + (KK) * 64, &As[BUF][ldsOff[0]]);            \
    GLOAD16(gAsrc[1] + (KK) * 64, &As[BUF][ldsOff[1]]);            \
    GLOAD16(gAsrc[2] + (KK) * 64, &As[BUF][ldsOff[2]]);            \
    GLOAD16(gAsrc[3] + (KK) * 64, &As[BUF][ldsOff[3]]);            \
    GLOAD16(gBsrc[0] + (KK) * 64, &Bs[BUF][ldsOff[0]]);            \
    GLOAD16(gBsrc[1] + (KK) * 64, &Bs[BUF][ldsOff[1]]);            \
    GLOAD16(gBsrc[2] + (KK) * 64, &Bs[BUF][ldsOff[2]]);            \
    GLOAD16(gBsrc[3] + (KK) * 64, &Bs[BUF][ldsOff[3]]);            \
  } while (0)

  f32x4 acc[4][4];
#pragma unroll
  for (int i = 0; i < 4; ++i)
#pragma unroll
    for (int j = 0; j < 4; ++j) acc[i][j] = (f32x4)0.0f;

#define COMPUTE(BUF) do {                                                       \
    _Pragma("unroll")                                                           \
    for (int h = 0; h < 2; ++h) {                                               \
      bf16x8 af[4], bfr[4];                                                     \
      _Pragma("unroll")                                                         \
      for (int i = 0; i < 4; ++i) {                                             \
        const int row = wo * 64 + i * 16 + lrow;                                \
        af[i] = *(const bf16x8*)&As[BUF][row * 64 +                             \
                   (((h * 4 + lks) ^ (row & 7)) * 8)];                          \
      }                                                                         \
      _Pragma("unroll")                                                         \
      for (int j = 0; j < 4; ++j) {                                             \
        const int row = wn * 64 + j * 16 + lrow;                                \
        bfr[j] = *(const bf16x8*)&Bs[BUF][row * 64 +                            \
                   (((h * 4 + lks) ^ (row & 7)) * 8)];                          \
      }                                                                         \
      __builtin_amdgcn_s_setprio(1);                                            \
      _Pragma("unroll")                                                         \
      for (int i = 0; i < 4; ++i)                                               \
        _Pragma("unroll")                                                       \
        for (int j = 0; j < 4; ++j)                                             \
          acc[i][j] = __builtin_amdgcn_mfma_f32_16x16x32_bf16(af[i], bfr[j],    \
                                                              acc[i][j], 0,0,0);\
      __builtin_amdgcn_s_setprio(0);                                            \
    }                                                                           \
  } while (0)

#define WAITBAR(N) do {                                                         \
    asm volatile("s_waitcnt vmcnt(" #N ")" ::: "memory");                       \
    __builtin_amdgcn_sched_barrier(0);                                          \
    __builtin_amdgcn_s_barrier();                                               \
    __builtin_amdgcn_sched_barrier(0);                                          \
  } while (0)

#define ENDBAR() do {                                                           \
    asm volatile("s_waitcnt lgkmcnt(0)" ::: "memory");                          \
    __builtin_amdgcn_sched_barrier(0);                                          \
    __builtin_amdgcn_s_barrier();                                               \
    __builtin_amdgcn_sched_barrier(0);                                          \
  } while (0)

  STAGE(0, 0);
  STAGE(1, 1);  WAITBAR(8);  COMPUTE(0);  ENDBAR();
  STAGE(0, 2);  WAITBAR(8);  COMPUTE(1);  ENDBAR();
  STAGE(1, 3);  WAITBAR(8);  COMPUTE(0);  ENDBAR();
                WAITBAR(0);  COMPUTE(1);
#undef WAITBAR
#undef ENDBAR
#undef STAGE
#undef COMPUTE

  // ---- epilogue: bias add, write bf16 layout [b][ti][c][tj][16]
#pragma unroll
  for (int i = 0; i < 4; ++i) {
    const int obase = o0 + wo * 64 + i * 16 + (lane >> 4) * 4;
#pragma unroll
    for (int j = 0; j < 4; ++j) {
      const int n  = n0 + wn * 64 + j * 16 + (lane & 15);
      const int bb = n >> 12;
      const int pp = n & 4095;
      const int tt = pp >> 4;
      const int tii = tt >> 4;
      const int tjj = tt & 15;
      const int dd  = pp & 15;
      const size_t base = ((size_t)(bb * 16 + tii) * 256) * 256 + tjj * 16 + dd;
#pragma unroll
      for (int r = 0; r < 4; ++r) {
        const int o = obase + r;
        const float v = acc[i][j][r] + bias[o];
        Out[base + (size_t)o * 256] = (__bf16)v;
      }
    }
  }
}

// ---------------- fallback: round-2 self-contained projection ----------------
__global__ __launch_bounds__(256) void proj_gemm_kernel(
    const float* __restrict__ blue, const float* __restrict__ white,
    const float* __restrict__ Wq, const float* __restrict__ bq,
    const float* __restrict__ Wk, const float* __restrict__ bk,
    const float* __restrict__ Wv, const float* __restrict__ bv,
    __bf16* __restrict__ Qt, __bf16* __restrict__ Kt, __bf16* __restrict__ Vt)
{
  __shared__ __bf16 As[128 * LROW];
  __shared__ __bf16 Bs[128 * LROW];

  const int bidhw = blockIdx.x;
  const int lid   = (bidhw & 7) * 192 + (bidhw >> 3);
  const int nb    = lid / 6;
  const int bt    = lid % 6;
  const int tensor = (bt < 4) ? 1 + (bt & 1) : 0;
  const int ob     = (bt < 4) ? (bt >> 1) : (bt & 1);

  const float* X    = (tensor == 0) ? blue : white;
  const float* W    = (tensor == 0) ? Wq : (tensor == 1) ? Wk : Wv;
  const float* bias = (tensor == 0) ? bq : (tensor == 1) ? bk : bv;
  __bf16*      Out  = (tensor == 0) ? Qt : (tensor == 1) ? Kt : Vt;

  const int tid  = threadIdx.x;
  const int lane = tid & 63;
  const int wave = tid >> 6;
  const int wo   = wave >> 1;
  const int wn   = wave & 1;

  const int o0 = ob * 128;
  const int n0 = nb * 128;
  const int batch = n0 >> 12;
  const int p0    = n0 & 4095;
  const int tk0   = p0 >> 4;
  const int trow  = tk0 >> 4;
  const int tcol0 = tk0 & 15;
  const float* Xb = X + (size_t)batch * (256 * 4096);

  f32x4 acc[4][4];
#pragma unroll
  for (int i = 0; i < 4; ++i)
#pragma unroll
    for (int j = 0; j < 4; ++j) acc[i][j] = (f32x4)0.0f;

  const int arow  = tid >> 1;
  const int ahalf = tid & 1;
  const int n2   = tid & 63;
  const int ko   = tid >> 6;
  const int nloc = 2 * n2;
  const int tl   = nloc >> 4;
  const int d    = nloc & 15;
  const int hw   = (trow * 4 + (d >> 2)) * 64 + (tcol0 + tl) * 4 + (d & 3);

  const int lrow = lane & 15;
  const int lk   = (lane >> 4) * 8;

  for (int kk = 0; kk < 8; ++kk) {
    const int k0 = kk * 32;
    {
      const float* src = W + (size_t)(o0 + arow) * 256 + k0 + ahalf * 16;
      f32x4 t0 = *(const f32x4*)(src + 0);
      f32x4 t1 = *(const f32x4*)(src + 4);
      f32x4 t2 = *(const f32x4*)(src + 8);
      f32x4 t3 = *(const f32x4*)(src + 12);
      bf16x8 c0, c1;
#pragma unroll
      for (int qq = 0; qq < 4; ++qq) { c0[qq] = (__bf16)t0[qq]; c0[qq + 4] = (__bf16)t1[qq]; }
#pragma unroll
      for (int qq = 0; qq < 4; ++qq) { c1[qq] = (__bf16)t2[qq]; c1[qq + 4] = (__bf16)t3[qq]; }
      __bf16* dst = As + arow * LROW + ahalf * 16;
      *(bf16x8*)(dst + 0) = c0;
      *(bf16x8*)(dst + 8) = c1;
    }
    {
      const float* src = Xb + (size_t)(k0 + ko * 8) * 4096 + hw;
      f32x2 v0 = *(const f32x2*)(src + 0 * 4096);
      f32x2 v1 = *(const f32x2*)(src + 1 * 4096);
      f32x2 v2 = *(const f32x2*)(src + 2 * 4096);
      f32x2 v3 = *(const f32x2*)(src + 3 * 4096);
      f32x2 v4 = *(const f32x2*)(src + 4 * 4096);
      f32x2 v5 = *(const f32x2*)(src + 5 * 4096);
      f32x2 v6 = *(const f32x2*)(src + 6 * 4096);
      f32x2 v7 = *(const f32x2*)(src + 7 * 4096);
      bf16x8 r0, r1;
      r0[0] = (__bf16)v0[0]; r0[1] = (__bf16)v1[0]; r0[2] = (__bf16)v2[0]; r0[3] = (__bf16)v3[0];
      r0[4] = (__bf16)v4[0]; r0[5] = (__bf16)v5[0]; r0[6] = (__bf16)v6[0]; r0[7] = (__bf16)v7[0];
      r1[0] = (__bf16)v0[1]; r1[1] = (__bf16)v1[1]; r1[2] = (__bf16)v2[1]; r1[3] = (__bf16)v3[1];
      r1[4] = (__bf16)v4[1]; r1[5] = (__bf16)v5[1]; r1[6] = (__bf16)v6[1]; r1[7] = (__bf16)v7[1];
      *(bf16x8*)(Bs + (nloc + 0) * LROW + ko * 8) = r0;
      *(bf16x8*)(Bs + (nloc + 1) * LROW + ko * 8) = r1;
    }
    __syncthreads();

    bf16x8 a[4], b[4];
#pragma unroll
    for (int i = 0; i < 4; ++i)
      a[i] = *(const bf16x8*)(As + (wo * 64 + i * 16 + lrow) * LROW + lk);
#pragma unroll
    for (int j = 0; j < 4; ++j)
      b[j] = *(const bf16x8*)(Bs + (wn * 64 + j * 16 + lrow) * LROW + lk);
#pragma unroll
    for (int i = 0; i < 4; ++i)
#pragma unroll
      for (int j = 0; j < 4; ++j)
        acc[i][j] = __builtin_amdgcn_mfma_f32_16x16x32_bf16(a[i], b[j], acc[i][j], 0, 0, 0);
    __syncthreads();
  }

#pragma unroll
  for (int i = 0; i < 4; ++i) {
    const int obase = o0 + wo * 64 + i * 16 + (lane >> 4) * 4;
#pragma unroll
    for (int j = 0; j < 4; ++j) {
      const int n  = n0 + wn * 64 + j * 16 + (lane & 15);
      const int bb = n >> 12;
      const int p  = n & 4095;
      const int tt = p >> 4;
      const int tii = tt >> 4;
      const int tjj = tt & 15;
      const int dd  = p & 15;
      const size_t base = ((size_t)(bb * 16 + tii) * 256) * 256 + tjj * 16 + dd;
#pragma unroll
      for (int r = 0; r < 4; ++r) {
        const int o = obase + r;
        const float v = acc[i][j][r] + bias[o];
        Out[base + (size_t)o * 256] = (__bf16)v;
      }
    }
  }
}

// ---------------- fused neighborhood attention + residual ----------------
__device__ __forceinline__ void unpack8(const uint4 v, float* f) {
  const uint32_t u0 = v.x, u1 = v.y, u2 = v.z, u3 = v.w;
  f[0] = __uint_as_float(u0 << 16); f[1] = __uint_as_float(u0 & 0xffff0000u);
  f[2] = __uint_as_float(u1 << 16); f[3] = __uint_as_float(u1 & 0xffff0000u);
  f[4] = __uint_as_float(u2 << 16); f[5] = __uint_as_float(u2 & 0xffff0000u);
  f[6] = __uint_as_float(u3 << 16); f[7] = __uint_as_float(u3 & 0xffff0000u);
}

__global__ __launch_bounds__(256) void attn_kernel(
    const __bf16* __restrict__ Qt, const __bf16* __restrict__ Kt,
    const __bf16* __restrict__ Vt, const float* __restrict__ blue,
    float* __restrict__ out)
{
  const int j   = blockIdx.x;
  const int bid = (j & 7) * 256 + (j >> 3);
  const int cg  = bid & 15;
  const int ti  = (bid >> 4) & 15;
  const int b   = bid >> 8;

  const int tid = threadIdx.x;
  const int tj  = tid & 15;
  const int cl  = tid >> 4;
  const int c   = cg * 16 + cl;

  float q[16];
  {
    const __bf16* p = Qt + ((((size_t)b * 16 + ti) * 256 + c) * 16 + tj) * 16;
    unpack8(*(const uint4*)p, q);
    unpack8(*(const uint4*)(p + 8), q + 8);
  }

  float s[9];
#pragma unroll
  for (int n = 0; n < 9; ++n) {
    const int yi = ti + n / 3 - 1;
    const int yj = tj + n % 3 - 1;
    float dot = 0.0f;
    if (yi >= 0 && yi < 16 && yj >= 0 && yj < 16) {
      const __bf16* p = Kt + ((((size_t)b * 16 + yi) * 256 + c) * 16 + yj) * 16;
      float kf[16];
      unpack8(*(const uint4*)p, kf);
      unpack8(*(const uint4*)(p + 8), kf + 8);
#pragma unroll
      for (int dd = 0; dd < 16; ++dd) dot = fmaf(q[dd], kf[dd], dot);
    }
    s[n] = dot * 0.25f;
  }

  float m = s[0];
#pragma unroll
  for (int n = 1; n < 9; ++n) m = fmaxf(m, s[n]);
  float w[9], denom = 0.0f;
#pragma unroll
  for (int n = 0; n < 9; ++n) { w[n] = __expf(s[n] - m); denom += w[n]; }
  const float inv = 1.0f / denom;

  float o16[16];
#pragma unroll
  for (int dd = 0; dd < 16; ++dd) o16[dd] = 0.0f;
#pragma unroll
  for (int n = 0; n < 9; ++n) {
    const int yi = ti + n / 3 - 1;
    const int yj = tj + n % 3 - 1;
    if (yi >= 0 && yi < 16 && yj >= 0 && yj < 16) {
      const __bf16* p = Vt + ((((size_t)b * 16 + yi) * 256 + c) * 16 + yj) * 16;
      float vf[16];
      unpack8(*(const uint4*)p, vf);
      unpack8(*(const uint4*)(p + 8), vf + 8);
#pragma unroll
      for (int dd = 0; dd < 16; ++dd) o16[dd] = fmaf(w[n], vf[dd], o16[dd]);
    }
  }

  const size_t pbase = ((size_t)b * 256 + c) * 4096 + (size_t)(ti * 4) * 64 + tj * 4;
#pragma unroll
  for (int r = 0; r < 4; ++r) {
    f32x4 bl = *(const f32x4*)(blue + pbase + r * 64);
    f32x4 ov;
#pragma unroll
    for (int j2 = 0; j2 < 4; ++j2) ov[j2] = bl[j2] + o16[r * 4 + j2] * inv;
    *(f32x4*)(out + pbase + r * 64) = ov;
  }
}

// ---------------- launcher ----------------
extern "C" void kernel_launch(void* const* d_in, const int* in_sizes, int n_in,
                              void* d_out, int out_size, void* d_ws, size_t ws_size,
                              hipStream_t stream) {
  const float* blue  = (const float*)d_in[0];
  const float* white = (const float*)d_in[1];
  const float* Wq = (const float*)d_in[2];
  const float* bq = (const float*)d_in[3];
  const float* Wk = (const float*)d_in[4];
  const float* bk = (const float*)d_in[5];
  const float* Wv = (const float*)d_in[6];
  const float* bv = (const float*)d_in[7];
  float* out = (float*)d_out;

  const size_t tsz = (size_t)8 * 256 * 256 * 16;   // QKV elems per tensor
  const size_t xsz = (size_t)8 * 4096 * 256;       // Xt elems per input
  __bf16* Qt = (__bf16*)d_ws;
  __bf16* Kt = Qt + tsz;
  __bf16* Vt = Kt + tsz;

  const size_t need = (3 * tsz + 2 * xsz + 3 * 65536) * sizeof(__bf16);
  if (ws_size >= need) {
    __bf16* Xtb = Vt + tsz;
    __bf16* Xtw = Xtb + xsz;
    __bf16* Wbf = Xtw + xsz;
    prep_kernel<<<259, 1024, 0, stream>>>(blue, white, Wq, Wk, Wv, Xtb, Xtw, Wbf);
    gemm_bk64_kernel<<<1536, 256, 0, stream>>>(Xtb, Xtw, Wbf, bq, bk, bv, Qt, Kt, Vt);
  } else {
    proj_gemm_kernel<<<1536, 256, 0, stream>>>(blue, white, Wq, bq, Wk, bk, Wv, bv, Qt, Kt, Vt);
  }
  attn_kernel<<<2048, 256, 0, stream>>>(Qt, Kt, Vt, blue, out);
}